// Round 2
// baseline (917.329 us; speedup 1.0000x reference)
//
#include <hip/hip_runtime.h>
#include <math.h>

#define ND 256
#define ED 32
#define H1 5
#define NG 64

__device__ __forceinline__ float sigf(float z) {
    return 1.0f / (1.0f + __expf(-z));
}

// ---------------------------------------------------------------------------
// Kernel 1: layer-1 node projections.
// kqv row layout (16 floats, 64B-aligned): [0..4]=q, [5..9]=v, [10..14]=k, [15]=0
// h[n][0..4] = x@Ws1 + b1  (root term; edge1 atomically accumulates into this).
// ---------------------------------------------------------------------------
__global__ void node_proj1(const float* __restrict__ x,
                           const float* __restrict__ Wk, const float* __restrict__ bk,
                           const float* __restrict__ Wq, const float* __restrict__ bq,
                           const float* __restrict__ Wv, const float* __restrict__ bv,
                           const float* __restrict__ Ws, const float* __restrict__ br,
                           float* __restrict__ kqv, float* __restrict__ h, int N)
{
    int n = blockIdx.x * blockDim.x + threadIdx.x;
    if (n >= N) return;

    float acc[20];
#pragma unroll
    for (int c = 0; c < H1; c++) {
        acc[c]      = bk[c];   // k
        acc[5 + c]  = bq[c];   // q
        acc[10 + c] = bv[c];   // v
        acc[15 + c] = br[c];   // root
    }

    const float4* X4 = (const float4*)(x + (size_t)n * ND);
#pragma unroll 2
    for (int j4 = 0; j4 < ND / 4; j4++) {
        float4 xv = X4[j4];
        float xr[4] = {xv.x, xv.y, xv.z, xv.w};
#pragma unroll
        for (int r = 0; r < 4; r++) {
            int j = j4 * 4 + r;
#pragma unroll
            for (int c = 0; c < H1; c++) {
                acc[c]      += xr[r] * Wk[j * H1 + c];
                acc[5 + c]  += xr[r] * Wq[j * H1 + c];
                acc[10 + c] += xr[r] * Wv[j * H1 + c];
                acc[15 + c] += xr[r] * Ws[j * H1 + c];
            }
        }
    }

    float* row = kqv + (size_t)n * 16;
#pragma unroll
    for (int c = 0; c < H1; c++) {
        row[c]      = acc[5 + c];   // q
        row[5 + c]  = acc[10 + c];  // v
        row[10 + c] = acc[c];       // k
    }
    row[15] = 0.0f;
#pragma unroll
    for (int c = 0; c < H1; c++) h[(size_t)n * H1 + c] = acc[15 + c];
}

// ---------------------------------------------------------------------------
// Kernel 2: fused layer-1 edge pass.
// Per edge: project edge_attr -> e1[5], e2; gather q/v of src and k of dst
// from the L2/LLC-hot kqv table; compute gated message; 5 atomicAdds into
// h[dst] (2 MB, L2-resident); store e2 in ORIGINAL edge order (coalesced).
// Replaces hist/scan/edge_scatter/aggregate1 and the 51 MB scattered record
// array (whose 64B-line RFO traffic dominated the old edge_scatter).
// ---------------------------------------------------------------------------
__global__ void edge1(const float* __restrict__ ea, const int* __restrict__ ei,
                      const float* __restrict__ We1, const float* __restrict__ be1,
                      const float* __restrict__ We2, const float* __restrict__ be2,
                      const float* __restrict__ kqv, float* __restrict__ h,
                      float* __restrict__ e2buf, int E)
{
    int e = blockIdx.x * blockDim.x + threadIdx.x;
    if (e >= E) return;

    // Per-thread row read: 8 x float4, thread-contiguous. Lanes stride 128B,
    // but every touched 64B line is fully consumed within the wave's 8 loads
    // (full line utilization, streaming).
    const float4* A4 = (const float4*)(ea + (size_t)e * ED);
    float4 r[8];
#pragma unroll
    for (int j = 0; j < 8; j++) r[j] = A4[j];

    int s = ei[e];
    int d = ei[E + e];

    float e10 = be1[0], e11 = be1[1], e12 = be1[2], e13 = be1[3], e14 = be1[4];
    float e2  = be2[0];
#pragma unroll
    for (int j4 = 0; j4 < 8; j4++) {
        float av[4] = {r[j4].x, r[j4].y, r[j4].z, r[j4].w};
#pragma unroll
        for (int t = 0; t < 4; t++) {
            int j = j4 * 4 + t;
            float a = av[t];
            e10 += a * We1[j * H1 + 0];
            e11 += a * We1[j * H1 + 1];
            e12 += a * We1[j * H1 + 2];
            e13 += a * We1[j * H1 + 3];
            e14 += a * We1[j * H1 + 4];
            e2  += a * We2[j];
        }
    }

    const float4* srow = (const float4*)(kqv + (size_t)s * 16);
    float4 q0 = srow[0];  // q0 q1 q2 q3
    float4 q1 = srow[1];  // q4 v0 v1 v2
    float4 q2 = srow[2];  // v3 v4 k0 k1
    const float4* drow = (const float4*)(kqv + (size_t)d * 16);
    float4 kA = drow[2];  // v3 v4 k0 k1
    float4 kB = drow[3];  // k2 k3 k4 0

    float m0 = sigf(kA.z + q0.x + 2.0f * e10) * (q1.y + e10);
    float m1 = sigf(kA.w + q0.y + 2.0f * e11) * (q1.z + e11);
    float m2 = sigf(kB.x + q0.z + 2.0f * e12) * (q1.w + e12);
    float m3 = sigf(kB.y + q0.w + 2.0f * e13) * (q2.x + e13);
    float m4 = sigf(kB.z + q1.x + 2.0f * e14) * (q2.y + e14);

    float* hd = h + (size_t)d * H1;
    atomicAdd(hd + 0, m0);
    atomicAdd(hd + 1, m1);
    atomicAdd(hd + 2, m2);
    atomicAdd(hd + 3, m3);
    atomicAdd(hd + 4, m4);

    e2buf[e] = e2;
}

// ---------------------------------------------------------------------------
// Kernel 3: GraphNorm stats (batch_idx sorted, binary search, no atomics).
// ---------------------------------------------------------------------------
__global__ void norm_reduce(const float* __restrict__ h, const int* __restrict__ B,
                            const float* __restrict__ gw, const float* __restrict__ gb,
                            const float* __restrict__ gms,
                            float* __restrict__ scale, float* __restrict__ shift, int N)
{
    int g = blockIdx.x;

    int lo = 0, hi = N;
    while (lo < hi) { int mid = (lo + hi) >> 1; if (B[mid] < g) lo = mid + 1; else hi = mid; }
    int start = lo;
    hi = N;
    while (lo < hi) { int mid = (lo + hi) >> 1; if (B[mid] < g + 1) lo = mid + 1; else hi = mid; }
    int end = lo;

    float sum[H1] = {0, 0, 0, 0, 0};
    float sq[H1]  = {0, 0, 0, 0, 0};
    for (int i = start + threadIdx.x; i < end; i += blockDim.x) {
#pragma unroll
        for (int c = 0; c < H1; c++) {
            float v = h[(size_t)i * H1 + c];
            sum[c] += v;
            sq[c]  += v * v;
        }
    }

#pragma unroll
    for (int off = 32; off >= 1; off >>= 1) {
#pragma unroll
        for (int c = 0; c < H1; c++) {
            sum[c] += __shfl_xor(sum[c], off);
            sq[c]  += __shfl_xor(sq[c], off);
        }
    }

    __shared__ float ls[4][2 * H1];
    int wave = threadIdx.x >> 6;
    int lane = threadIdx.x & 63;
    if (lane == 0) {
#pragma unroll
        for (int c = 0; c < H1; c++) { ls[wave][c] = sum[c]; ls[wave][H1 + c] = sq[c]; }
    }
    __syncthreads();

    if (threadIdx.x == 0) {
        float cnt = fmaxf((float)(end - start), 1.0f);
#pragma unroll
        for (int c = 0; c < H1; c++) {
            float s0 = ls[0][c] + ls[1][c] + ls[2][c] + ls[3][c];
            float q0 = ls[0][H1 + c] + ls[1][H1 + c] + ls[2][H1 + c] + ls[3][H1 + c];
            float mean = s0 / cnt;
            float ms   = gms[c];
            float var  = q0 / cnt - mean * mean * ms * (2.0f - ms);
            float inv  = rsqrtf(var + 1e-5f);
            float sc   = gw[c] * inv;
            scale[g * H1 + c] = sc;
            shift[g * H1 + c] = gb[c] - sc * mean * ms;
        }
    }
}

// ---------------------------------------------------------------------------
// Kernel 4: apply norm + ReLU + layer-2 node projections.
// kqv2[n] = {k2, q2, v2, 0}; root2[n] = h2 @ Ws2 + b2.
// ---------------------------------------------------------------------------
__global__ void norm_apply_proj2(const float* __restrict__ h, const int* __restrict__ B,
                                 const float* __restrict__ scale, const float* __restrict__ shift,
                                 const float* __restrict__ Wk2, const float* __restrict__ bk2,
                                 const float* __restrict__ Wq2, const float* __restrict__ bq2,
                                 const float* __restrict__ Wv2, const float* __restrict__ bv2,
                                 const float* __restrict__ Ws2, const float* __restrict__ b2,
                                 float4* __restrict__ kqv2, float* __restrict__ root2, int N)
{
    int n = blockIdx.x * blockDim.x + threadIdx.x;
    if (n >= N) return;

    int g = B[n];
    float k2 = bk2[0], q2 = bq2[0], v2 = bv2[0], s2 = b2[0];
#pragma unroll
    for (int c = 0; c < H1; c++) {
        float hn = scale[g * H1 + c] * h[(size_t)n * H1 + c] + shift[g * H1 + c];
        hn = fmaxf(hn, 0.0f);
        k2 += hn * Wk2[c];
        q2 += hn * Wq2[c];
        v2 += hn * Wv2[c];
        s2 += hn * Ws2[c];
    }
    kqv2[n]  = make_float4(k2, q2, v2, 0.0f);
    root2[n] = s2;
}

// ---------------------------------------------------------------------------
// Kernel 5: layer-2 edge pass. Two 16B gathers from the 1.6 MB kqv2 table
// (L2-resident) + one atomicAdd into mbuf[dst] (0.4 MB, L2-resident).
// ---------------------------------------------------------------------------
__global__ void edge2(const int* __restrict__ ei, const float* __restrict__ e2buf,
                      const float4* __restrict__ kqv2, float* __restrict__ mbuf, int E)
{
    int e = blockIdx.x * blockDim.x + threadIdx.x;
    if (e >= E) return;

    int s = ei[e];
    int d = ei[E + e];
    float e2 = e2buf[e];
    float4 sv = kqv2[s];
    float kd = kqv2[d].x;
    float m = sigf(kd + sv.y + 2.0f * e2) * (sv.z + e2);
    atomicAdd(&mbuf[d], m);
}

// ---------------------------------------------------------------------------
// Kernel 6: final sigmoid.
// ---------------------------------------------------------------------------
__global__ void finalize(const float* __restrict__ root2, const float* __restrict__ mbuf,
                         float* __restrict__ out, int N)
{
    int n = blockIdx.x * blockDim.x + threadIdx.x;
    if (n < N) out[n] = sigf(root2[n] + mbuf[n]);
}

// ---------------------------------------------------------------------------
extern "C" void kernel_launch(void* const* d_in, const int* in_sizes, int n_in,
                              void* d_out, int out_size, void* d_ws, size_t ws_size,
                              hipStream_t stream)
{
    const float* x   = (const float*)d_in[0];
    const float* ea  = (const float*)d_in[1];
    const int*   ei  = (const int*)d_in[2];
    const int*   B   = (const int*)d_in[3];
    const float* Wk1 = (const float*)d_in[4];
    const float* bk1 = (const float*)d_in[5];
    const float* Wq1 = (const float*)d_in[6];
    const float* bq1 = (const float*)d_in[7];
    const float* Wv1 = (const float*)d_in[8];
    const float* bv1 = (const float*)d_in[9];
    const float* We1 = (const float*)d_in[10];
    const float* be1 = (const float*)d_in[11];
    const float* Ws1 = (const float*)d_in[12];
    const float* b1  = (const float*)d_in[13];
    const float* gw  = (const float*)d_in[14];
    const float* gb  = (const float*)d_in[15];
    const float* gms = (const float*)d_in[16];
    const float* Wk2 = (const float*)d_in[17];
    const float* bk2 = (const float*)d_in[18];
    const float* Wq2 = (const float*)d_in[19];
    const float* bq2 = (const float*)d_in[20];
    const float* Wv2 = (const float*)d_in[21];
    const float* bv2 = (const float*)d_in[22];
    const float* We2 = (const float*)d_in[23];
    const float* be2 = (const float*)d_in[24];
    const float* Ws2 = (const float*)d_in[25];
    const float* b2  = (const float*)d_in[26];

    const int N = in_sizes[0] / ND;   // 100000
    const int E = in_sizes[1] / ED;   // 1600000

    // Workspace layout (floats), all segments 16B-aligned (N, E mult of 4).
    float* ws     = (float*)d_ws;
    float* kqv    = ws;                               // N*16
    float* h      = kqv + (size_t)N * 16;             // N*5
    float* e2buf  = h + (size_t)N * H1;               // E
    float* scale  = e2buf + (size_t)E;                // NG*5
    float* shift  = scale + NG * H1;                  // NG*5
    float* kqv2f  = shift + NG * H1;                  // N*4  (320+320 = 640 -> 16B aligned)
    float* root2  = kqv2f + (size_t)N * 4;            // N
    float* mbuf   = root2 + (size_t)N;                // N
    float4* kqv2  = (float4*)kqv2f;

    dim3 blk(256);
    dim3 gN((N + 255) / 256);
    dim3 gE((E + 255) / 256);

    hipMemsetAsync(mbuf, 0, (size_t)N * sizeof(float), stream);

    node_proj1<<<gN, blk, 0, stream>>>(x, Wk1, bk1, Wq1, bq1, Wv1, bv1, Ws1, b1,
                                       kqv, h, N);
    edge1<<<gE, blk, 0, stream>>>(ea, ei, We1, be1, We2, be2, kqv, h, e2buf, E);
    norm_reduce<<<NG, blk, 0, stream>>>(h, B, gw, gb, gms, scale, shift, N);
    norm_apply_proj2<<<gN, blk, 0, stream>>>(h, B, scale, shift,
                                             Wk2, bk2, Wq2, bq2, Wv2, bv2, Ws2, b2,
                                             kqv2, root2, N);
    edge2<<<gE, blk, 0, stream>>>(ei, e2buf, kqv2, mbuf, E);
    finalize<<<gN, blk, 0, stream>>>(root2, mbuf, (float*)d_out, N);
}

// Round 4
// 758.201 us; speedup vs baseline: 1.2099x; 1.2099x over previous
//
#include <hip/hip_runtime.h>
#include <math.h>

#define ND 256
#define ED 32
#define H1 5
#define NG 64
#define SCAN_TILE 1024

__device__ __forceinline__ float sigf(float z) {
    return 1.0f / (1.0f + __expf(-z));
}

// ---------------------------------------------------------------------------
// Kernel 1: layer-1 node projections.
// kqv row layout (16 floats, 64B-aligned): [0..4]=q, [5..9]=v, [10..14]=k, [15]=0
// h[n][0..4] = x@Ws1 + b1  (root term; aggregate1 adds messages later).
// ---------------------------------------------------------------------------
__global__ void node_proj1(const float* __restrict__ x,
                           const float* __restrict__ Wk, const float* __restrict__ bk,
                           const float* __restrict__ Wq, const float* __restrict__ bq,
                           const float* __restrict__ Wv, const float* __restrict__ bv,
                           const float* __restrict__ Ws, const float* __restrict__ br,
                           float* __restrict__ kqv, float* __restrict__ h, int N)
{
    int n = blockIdx.x * blockDim.x + threadIdx.x;
    if (n >= N) return;

    float acc[20];
#pragma unroll
    for (int c = 0; c < H1; c++) {
        acc[c]      = bk[c];   // k
        acc[5 + c]  = bq[c];   // q
        acc[10 + c] = bv[c];   // v
        acc[15 + c] = br[c];   // root
    }

    const float4* X4 = (const float4*)(x + (size_t)n * ND);
#pragma unroll 2
    for (int j4 = 0; j4 < ND / 4; j4++) {
        float4 xv = X4[j4];
        float xr[4] = {xv.x, xv.y, xv.z, xv.w};
#pragma unroll
        for (int r = 0; r < 4; r++) {
            int j = j4 * 4 + r;
#pragma unroll
            for (int c = 0; c < H1; c++) {
                acc[c]      += xr[r] * Wk[j * H1 + c];
                acc[5 + c]  += xr[r] * Wq[j * H1 + c];
                acc[10 + c] += xr[r] * Wv[j * H1 + c];
                acc[15 + c] += xr[r] * Ws[j * H1 + c];
            }
        }
    }

    float* row = kqv + (size_t)n * 16;
#pragma unroll
    for (int c = 0; c < H1; c++) {
        row[c]      = acc[5 + c];   // q
        row[5 + c]  = acc[10 + c];  // v
        row[10 + c] = acc[c];       // k
    }
    row[15] = 0.0f;
#pragma unroll
    for (int c = 0; c < H1; c++) h[(size_t)n * H1 + c] = acc[15 + c];
}

// ---------------------------------------------------------------------------
// Kernel 2: degree histogram over dst (int atomics, proven cheap).
// ---------------------------------------------------------------------------
__global__ void hist_dst(const int* __restrict__ ei, int* __restrict__ cnt, int E)
{
    int e = blockIdx.x * blockDim.x + threadIdx.x;
    if (e < E) atomicAdd(&cnt[ei[E + e]], 1);
}

// ---------------------------------------------------------------------------
// Kernels 3a/3b/3c: parallel exclusive scan of cnt[N] -> offs[N+1] + cursor[N].
// (verbatim from the verified 654us session)
// ---------------------------------------------------------------------------
__global__ void scan_part(const int* __restrict__ cnt, int* __restrict__ bsum, int N)
{
    int t = threadIdx.x;
    int base = blockIdx.x * SCAN_TILE + t * 4;
    int s = 0;
    if (base + 3 < N) {
        int4 v = *(const int4*)(cnt + base);
        s = v.x + v.y + v.z + v.w;
    } else {
        for (int i = 0; i < 4; i++) if (base + i < N) s += cnt[base + i];
    }
#pragma unroll
    for (int off = 32; off >= 1; off >>= 1) s += __shfl_xor(s, off);
    __shared__ int wsum[4];
    if ((t & 63) == 0) wsum[t >> 6] = s;
    __syncthreads();
    if (t == 0) bsum[blockIdx.x] = wsum[0] + wsum[1] + wsum[2] + wsum[3];
}

__global__ void scan_blocksums(int* __restrict__ bsum, int nb)
{
    __shared__ int a[1024], b[1024];
    int t = threadIdx.x;
    int v = (t < nb) ? bsum[t] : 0;
    a[t] = v;
    __syncthreads();
    int* in = a; int* out = b;
    for (int off = 1; off < 1024; off <<= 1) {
        out[t] = in[t] + ((t >= off) ? in[t - off] : 0);
        __syncthreads();
        int* tmp = in; in = out; out = tmp;
    }
    if (t < nb) bsum[t] = in[t] - v;  // exclusive prefix
}

__global__ void scan_final(const int* __restrict__ cnt, const int* __restrict__ bsum,
                           int* __restrict__ offs, int* __restrict__ cursor, int N, int E)
{
    int t = threadIdx.x;
    int lane = t & 63;
    int wave = t >> 6;
    int base = blockIdx.x * SCAN_TILE + t * 4;

    int v0 = 0, v1 = 0, v2 = 0, v3 = 0;
    if (base + 3 < N) {
        int4 v = *(const int4*)(cnt + base);
        v0 = v.x; v1 = v.y; v2 = v.z; v3 = v.w;
    } else {
        if (base + 0 < N) v0 = cnt[base + 0];
        if (base + 1 < N) v1 = cnt[base + 1];
        if (base + 2 < N) v2 = cnt[base + 2];
        if (base + 3 < N) v3 = cnt[base + 3];
    }
    int s = v0 + v1 + v2 + v3;

    int inc = s;
#pragma unroll
    for (int off = 1; off < 64; off <<= 1) {
        int u = __shfl_up(inc, off);
        if (lane >= off) inc += u;
    }

    __shared__ int wtot[4];
    if (lane == 63) wtot[wave] = inc;
    __syncthreads();
    int woff = 0;
#pragma unroll
    for (int w = 0; w < 4; w++) woff += (w < wave) ? wtot[w] : 0;

    int excl = bsum[blockIdx.x] + woff + (inc - s);

    if (base < N) {
        int p0 = excl, p1 = p0 + v0, p2 = p1 + v1, p3 = p2 + v2;
        if (base + 3 < N) {
            *(int4*)(offs + base)   = make_int4(p0, p1, p2, p3);
            *(int4*)(cursor + base) = make_int4(p0, p1, p2, p3);
        } else {
            if (base + 0 < N) { offs[base + 0] = p0; cursor[base + 0] = p0; }
            if (base + 1 < N) { offs[base + 1] = p1; cursor[base + 1] = p1; }
            if (base + 2 < N) { offs[base + 2] = p2; cursor[base + 2] = p2; }
            if (base + 3 < N) { offs[base + 3] = p3; cursor[base + 3] = p3; }
        }
    }
    if (blockIdx.x == 0 && t == 0) offs[N] = E;
}

// ---------------------------------------------------------------------------
// Kernel 4: fused edge pass, all COALESCED except a 4B id scatter.
// Per edge: stream ea row, gather kqv[src] (q,v) + kqv[dst] (k) from the
// L2/LLC-hot 6.4MB table, compute final messages m0..m4 and e2, write
// recA[e]={m0..m3} (16B) and recB[e]={m4,e2} (8B) coalesced in edge order,
// and scatter only the 4B edge id into CSR position (int atomic + 4B write).
// ---------------------------------------------------------------------------
__global__ void edge_msg(const float* __restrict__ ea, const int* __restrict__ ei,
                         const float* __restrict__ We1, const float* __restrict__ be1,
                         const float* __restrict__ We2, const float* __restrict__ be2,
                         const float* __restrict__ kqv, int* __restrict__ cursor,
                         float4* __restrict__ recA, float2* __restrict__ recB,
                         int* __restrict__ perm, int E)
{
    int e = blockIdx.x * blockDim.x + threadIdx.x;
    if (e >= E) return;

    // 8 x float4 per-thread row read; the wave's bursts cover a contiguous
    // 8KB span, every 64B line fully consumed.
    const float4* A4 = (const float4*)(ea + (size_t)e * ED);
    float4 r[8];
#pragma unroll
    for (int j = 0; j < 8; j++) r[j] = A4[j];

    int s = ei[e];
    int d = ei[E + e];
    int pos = atomicAdd(&cursor[d], 1);   // issue early; latency hides under FMAs

    // issue gathers early too
    const float4* srow = (const float4*)(kqv + (size_t)s * 16);
    float4 q0 = srow[0];  // q0 q1 q2 q3
    float4 q1 = srow[1];  // q4 v0 v1 v2
    float4 q2 = srow[2];  // v3 v4 k0 k1
    const float4* drow = (const float4*)(kqv + (size_t)d * 16);
    float4 kA = drow[2];  // v3 v4 k0 k1
    float4 kB = drow[3];  // k2 k3 k4 0

    float e10 = be1[0], e11 = be1[1], e12 = be1[2], e13 = be1[3], e14 = be1[4];
    float e2  = be2[0];
#pragma unroll
    for (int j4 = 0; j4 < 8; j4++) {
        float av[4] = {r[j4].x, r[j4].y, r[j4].z, r[j4].w};
#pragma unroll
        for (int t = 0; t < 4; t++) {
            int j = j4 * 4 + t;
            float a = av[t];
            e10 += a * We1[j * H1 + 0];
            e11 += a * We1[j * H1 + 1];
            e12 += a * We1[j * H1 + 2];
            e13 += a * We1[j * H1 + 3];
            e14 += a * We1[j * H1 + 4];
            e2  += a * We2[j];
        }
    }

    float m0 = sigf(kA.z + q0.x + 2.0f * e10) * (q1.y + e10);
    float m1 = sigf(kA.w + q0.y + 2.0f * e11) * (q1.z + e11);
    float m2 = sigf(kB.x + q0.z + 2.0f * e12) * (q1.w + e12);
    float m3 = sigf(kB.y + q0.w + 2.0f * e13) * (q2.x + e13);
    float m4 = sigf(kB.z + q1.x + 2.0f * e14) * (q2.y + e14);

    recA[e] = make_float4(m0, m1, m2, m3);
    recB[e] = make_float2(m4, e2);

    perm[pos] = e;
}

// ---------------------------------------------------------------------------
// Kernel 5: layer-1 aggregation. 16 lanes per node, coalesced perm read,
// random 16B+8B rec gathers (38MB, LLC-resident), pure adds.
// ---------------------------------------------------------------------------
__global__ void aggregate1(const int* __restrict__ perm, const int* __restrict__ offs,
                           const float4* __restrict__ recA, const float2* __restrict__ recB,
                           float* __restrict__ h, int N)
{
    int t = threadIdx.x;
    int n = blockIdx.x * 16 + (t >> 4);
    int lane = t & 15;
    if (n >= N) return;

    int start = offs[n], end = offs[n + 1];

    float m0 = 0, m1 = 0, m2 = 0, m3 = 0, m4 = 0;
    for (int i = start + lane; i < end; i += 16) {
        int e = perm[i];
        float4 a = recA[e];
        float2 b = recB[e];
        m0 += a.x; m1 += a.y; m2 += a.z; m3 += a.w; m4 += b.x;
    }

#pragma unroll
    for (int off = 8; off >= 1; off >>= 1) {
        m0 += __shfl_xor(m0, off);
        m1 += __shfl_xor(m1, off);
        m2 += __shfl_xor(m2, off);
        m3 += __shfl_xor(m3, off);
        m4 += __shfl_xor(m4, off);
    }

    if (lane == 0) {
        size_t base = (size_t)n * H1;
        h[base + 0] += m0;  // h holds root term from node_proj1
        h[base + 1] += m1;
        h[base + 2] += m2;
        h[base + 3] += m3;
        h[base + 4] += m4;
    }
}

// ---------------------------------------------------------------------------
// Kernel 6: GraphNorm stats (batch_idx sorted, binary search, no atomics).
// ---------------------------------------------------------------------------
__global__ void norm_reduce(const float* __restrict__ h, const int* __restrict__ B,
                            const float* __restrict__ gw, const float* __restrict__ gb,
                            const float* __restrict__ gms,
                            float* __restrict__ scale, float* __restrict__ shift, int N)
{
    int g = blockIdx.x;

    int lo = 0, hi = N;
    while (lo < hi) { int mid = (lo + hi) >> 1; if (B[mid] < g) lo = mid + 1; else hi = mid; }
    int start = lo;
    hi = N;
    while (lo < hi) { int mid = (lo + hi) >> 1; if (B[mid] < g + 1) lo = mid + 1; else hi = mid; }
    int end = lo;

    float sum[H1] = {0, 0, 0, 0, 0};
    float sq[H1]  = {0, 0, 0, 0, 0};
    for (int i = start + threadIdx.x; i < end; i += blockDim.x) {
#pragma unroll
        for (int c = 0; c < H1; c++) {
            float v = h[(size_t)i * H1 + c];
            sum[c] += v;
            sq[c]  += v * v;
        }
    }

#pragma unroll
    for (int off = 32; off >= 1; off >>= 1) {
#pragma unroll
        for (int c = 0; c < H1; c++) {
            sum[c] += __shfl_xor(sum[c], off);
            sq[c]  += __shfl_xor(sq[c], off);
        }
    }

    __shared__ float ls[4][2 * H1];
    int wave = threadIdx.x >> 6;
    int lane = threadIdx.x & 63;
    if (lane == 0) {
#pragma unroll
        for (int c = 0; c < H1; c++) { ls[wave][c] = sum[c]; ls[wave][H1 + c] = sq[c]; }
    }
    __syncthreads();

    if (threadIdx.x == 0) {
        float cnt = fmaxf((float)(end - start), 1.0f);
#pragma unroll
        for (int c = 0; c < H1; c++) {
            float s0 = ls[0][c] + ls[1][c] + ls[2][c] + ls[3][c];
            float q0 = ls[0][H1 + c] + ls[1][H1 + c] + ls[2][H1 + c] + ls[3][H1 + c];
            float mean = s0 / cnt;
            float ms   = gms[c];
            float var  = q0 / cnt - mean * mean * ms * (2.0f - ms);
            float inv  = rsqrtf(var + 1e-5f);
            float sc   = gw[c] * inv;
            scale[g * H1 + c] = sc;
            shift[g * H1 + c] = gb[c] - sc * mean * ms;
        }
    }
}

// ---------------------------------------------------------------------------
// Kernel 7: apply norm + ReLU + layer-2 node projections.
// ---------------------------------------------------------------------------
__global__ void norm_apply_proj2(const float* __restrict__ h, const int* __restrict__ B,
                                 const float* __restrict__ scale, const float* __restrict__ shift,
                                 const float* __restrict__ Wk2, const float* __restrict__ bk2,
                                 const float* __restrict__ Wq2, const float* __restrict__ bq2,
                                 const float* __restrict__ Wv2, const float* __restrict__ bv2,
                                 const float* __restrict__ Ws2, const float* __restrict__ b2,
                                 float4* __restrict__ kqv2, float* __restrict__ root2, int N)
{
    int n = blockIdx.x * blockDim.x + threadIdx.x;
    if (n >= N) return;

    int g = B[n];
    float k2 = bk2[0], q2 = bq2[0], v2 = bv2[0], s2 = b2[0];
#pragma unroll
    for (int c = 0; c < H1; c++) {
        float hn = scale[g * H1 + c] * h[(size_t)n * H1 + c] + shift[g * H1 + c];
        hn = fmaxf(hn, 0.0f);
        k2 += hn * Wk2[c];
        q2 += hn * Wq2[c];
        v2 += hn * Wv2[c];
        s2 += hn * Ws2[c];
    }
    kqv2[n]  = make_float4(k2, q2, v2, 0.0f);
    root2[n] = s2;
}

// ---------------------------------------------------------------------------
// Kernel 8: layer-2 aggregation + final sigmoid. Gathers recB (e2), ei (src)
// and kqv2 rows — all LLC-hot. No atomics.
// ---------------------------------------------------------------------------
__global__ void aggregate2(const int* __restrict__ perm, const int* __restrict__ offs,
                           const float2* __restrict__ recB, const int* __restrict__ ei,
                           const float4* __restrict__ kqv2, const float* __restrict__ root2,
                           float* __restrict__ out, int N)
{
    int t = threadIdx.x;
    int n = blockIdx.x * 16 + (t >> 4);
    int lane = t & 15;
    if (n >= N) return;

    int start = offs[n], end = offs[n + 1];
    float kd = kqv2[n].x;

    float m = 0;
    for (int i = start + lane; i < end; i += 16) {
        int e = perm[i];
        float2 b = recB[e];          // m4 e2
        float e2 = b.y;
        int s = ei[e];
        float4 sv = kqv2[s];
        m += sigf(kd + sv.y + 2.0f * e2) * (sv.z + e2);
    }

#pragma unroll
    for (int off = 8; off >= 1; off >>= 1) m += __shfl_xor(m, off);

    if (lane == 0) out[n] = sigf(root2[n] + m);
}

// ---------------------------------------------------------------------------
extern "C" void kernel_launch(void* const* d_in, const int* in_sizes, int n_in,
                              void* d_out, int out_size, void* d_ws, size_t ws_size,
                              hipStream_t stream)
{
    const float* x   = (const float*)d_in[0];
    const float* ea  = (const float*)d_in[1];
    const int*   ei  = (const int*)d_in[2];
    const int*   B   = (const int*)d_in[3];
    const float* Wk1 = (const float*)d_in[4];
    const float* bk1 = (const float*)d_in[5];
    const float* Wq1 = (const float*)d_in[6];
    const float* bq1 = (const float*)d_in[7];
    const float* Wv1 = (const float*)d_in[8];
    const float* bv1 = (const float*)d_in[9];
    const float* We1 = (const float*)d_in[10];
    const float* be1 = (const float*)d_in[11];
    const float* Ws1 = (const float*)d_in[12];
    const float* b1  = (const float*)d_in[13];
    const float* gw  = (const float*)d_in[14];
    const float* gb  = (const float*)d_in[15];
    const float* gms = (const float*)d_in[16];
    const float* Wk2 = (const float*)d_in[17];
    const float* bk2 = (const float*)d_in[18];
    const float* Wq2 = (const float*)d_in[19];
    const float* bq2 = (const float*)d_in[20];
    const float* Wv2 = (const float*)d_in[21];
    const float* bv2 = (const float*)d_in[22];
    const float* We2 = (const float*)d_in[23];
    const float* be2 = (const float*)d_in[24];
    const float* Ws2 = (const float*)d_in[25];
    const float* b2  = (const float*)d_in[26];

    const int N = in_sizes[0] / ND;   // 100000
    const int E = in_sizes[1] / ED;   // 1600000
    const int nb = (N + SCAN_TILE - 1) / SCAN_TILE;  // 98

    // Workspace layout (4B units), every segment 16B-aligned (N, E mult of 4).
    // Total ~56.9 MB (below the 62.9 MB footprint proven in the 654us session).
    float* ws     = (float*)d_ws;
    float* kqv    = ws;                                 // N*16      (6.4 MB)
    float* h      = kqv + (size_t)N * 16;               // N*5       (2 MB)
    float* recAf  = h + (size_t)N * H1;                 // E*4       (25.6 MB)
    float* recBf  = recAf + (size_t)E * 4;              // E*2       (12.8 MB)
    int*   perm   = (int*)(recBf + (size_t)E * 2);      // E         (6.4 MB)
    int*   cnt    = perm + (size_t)E;                   // N
    int*   offs   = cnt + N;                            // N+4 (pad)
    int*   cursor = offs + N + 4;                       // N
    int*   bsum   = cursor + N;                         // 1024
    float* scale  = (float*)(bsum + 1024);              // NG*5 = 320
    float* shift  = scale + NG * H1;                    // 320
    float* kqv2f  = shift + NG * H1;                    // N*4 (640 floats before -> 16B aligned)
    float* root2  = kqv2f + (size_t)N * 4;              // N
    float4* kqv2  = (float4*)kqv2f;
    float4* recA  = (float4*)recAf;
    float2* recB  = (float2*)recBf;

    dim3 blk(256);
    dim3 gN((N + 255) / 256);
    dim3 gE((E + 255) / 256);
    dim3 gAgg((N + 15) / 16);

    hipMemsetAsync(cnt, 0, (size_t)N * sizeof(int), stream);

    hist_dst<<<gE, blk, 0, stream>>>(ei, cnt, E);
    node_proj1<<<gN, blk, 0, stream>>>(x, Wk1, bk1, Wq1, bq1, Wv1, bv1, Ws1, b1,
                                       kqv, h, N);
    scan_part<<<nb, 256, 0, stream>>>(cnt, bsum, N);
    scan_blocksums<<<1, 1024, 0, stream>>>(bsum, nb);
    scan_final<<<nb, 256, 0, stream>>>(cnt, bsum, offs, cursor, N, E);
    edge_msg<<<gE, blk, 0, stream>>>(ea, ei, We1, be1, We2, be2, kqv, cursor,
                                     recA, recB, perm, E);
    aggregate1<<<gAgg, blk, 0, stream>>>(perm, offs, recA, recB, h, N);
    norm_reduce<<<NG, blk, 0, stream>>>(h, B, gw, gb, gms, scale, shift, N);
    norm_apply_proj2<<<gN, blk, 0, stream>>>(h, B, scale, shift,
                                             Wk2, bk2, Wq2, bq2, Wv2, bv2, Ws2, b2,
                                             kqv2, root2, N);
    aggregate2<<<gAgg, blk, 0, stream>>>(perm, offs, recB, ei, kqv2, root2,
                                         (float*)d_out, N);
}

// Round 6
// 741.215 us; speedup vs baseline: 1.2376x; 1.0229x over previous
//
#include <hip/hip_runtime.h>
#include <math.h>

#define ND 256
#define ED 32
#define H1 5
#define NG 64
#define SCAN_TILE 1024

__device__ __forceinline__ float sigf(float z) {
    return 1.0f / (1.0f + __expf(-z));
}

// ---------------------------------------------------------------------------
// Kernel 1: layer-1 node projections.
// kqv row layout (16 floats, 64B-aligned): [0..4]=q, [5..9]=v, [10..14]=k, [15]=0
// h[n][0..4] = x@Ws1 + b1  (root term; agg1 adds messages later).
// ---------------------------------------------------------------------------
__global__ void node_proj1(const float* __restrict__ x,
                           const float* __restrict__ Wk, const float* __restrict__ bk,
                           const float* __restrict__ Wq, const float* __restrict__ bq,
                           const float* __restrict__ Wv, const float* __restrict__ bv,
                           const float* __restrict__ Ws, const float* __restrict__ br,
                           float* __restrict__ kqv, float* __restrict__ h, int N)
{
    int n = blockIdx.x * blockDim.x + threadIdx.x;
    if (n >= N) return;

    float acc[20];
#pragma unroll
    for (int c = 0; c < H1; c++) {
        acc[c]      = bk[c];   // k
        acc[5 + c]  = bq[c];   // q
        acc[10 + c] = bv[c];   // v
        acc[15 + c] = br[c];   // root
    }

    const float4* X4 = (const float4*)(x + (size_t)n * ND);
#pragma unroll 2
    for (int j4 = 0; j4 < ND / 4; j4++) {
        float4 xv = X4[j4];
        float xr[4] = {xv.x, xv.y, xv.z, xv.w};
#pragma unroll
        for (int r = 0; r < 4; r++) {
            int j = j4 * 4 + r;
#pragma unroll
            for (int c = 0; c < H1; c++) {
                acc[c]      += xr[r] * Wk[j * H1 + c];
                acc[5 + c]  += xr[r] * Wq[j * H1 + c];
                acc[10 + c] += xr[r] * Wv[j * H1 + c];
                acc[15 + c] += xr[r] * Ws[j * H1 + c];
            }
        }
    }

    float* row = kqv + (size_t)n * 16;
#pragma unroll
    for (int c = 0; c < H1; c++) {
        row[c]      = acc[5 + c];   // q
        row[5 + c]  = acc[10 + c];  // v
        row[10 + c] = acc[c];       // k
    }
    row[15] = 0.0f;
#pragma unroll
    for (int c = 0; c < H1; c++) h[(size_t)n * H1 + c] = acc[15 + c];
}

// ---------------------------------------------------------------------------
// Kernel 2: degree histogram over dst (int atomics, proven cheap).
// ---------------------------------------------------------------------------
__global__ void hist_dst(const int* __restrict__ ei, int* __restrict__ cnt, int E)
{
    int e = blockIdx.x * blockDim.x + threadIdx.x;
    if (e < E) atomicAdd(&cnt[ei[E + e]], 1);
}

// ---------------------------------------------------------------------------
// Kernels 3a/3b/3c: parallel exclusive scan of cnt[N] -> offs[N+1] + cursor[N].
// (verbatim from the verified 654us session)
// ---------------------------------------------------------------------------
__global__ void scan_part(const int* __restrict__ cnt, int* __restrict__ bsum, int N)
{
    int t = threadIdx.x;
    int base = blockIdx.x * SCAN_TILE + t * 4;
    int s = 0;
    if (base + 3 < N) {
        int4 v = *(const int4*)(cnt + base);
        s = v.x + v.y + v.z + v.w;
    } else {
        for (int i = 0; i < 4; i++) if (base + i < N) s += cnt[base + i];
    }
#pragma unroll
    for (int off = 32; off >= 1; off >>= 1) s += __shfl_xor(s, off);
    __shared__ int wsum[4];
    if ((t & 63) == 0) wsum[t >> 6] = s;
    __syncthreads();
    if (t == 0) bsum[blockIdx.x] = wsum[0] + wsum[1] + wsum[2] + wsum[3];
}

__global__ void scan_blocksums(int* __restrict__ bsum, int nb)
{
    __shared__ int a[1024], b[1024];
    int t = threadIdx.x;
    int v = (t < nb) ? bsum[t] : 0;
    a[t] = v;
    __syncthreads();
    int* in = a; int* out = b;
    for (int off = 1; off < 1024; off <<= 1) {
        out[t] = in[t] + ((t >= off) ? in[t - off] : 0);
        __syncthreads();
        int* tmp = in; in = out; out = tmp;
    }
    if (t < nb) bsum[t] = in[t] - v;  // exclusive prefix
}

__global__ void scan_final(const int* __restrict__ cnt, const int* __restrict__ bsum,
                           int* __restrict__ offs, int* __restrict__ cursor, int N, int E)
{
    int t = threadIdx.x;
    int lane = t & 63;
    int wave = t >> 6;
    int base = blockIdx.x * SCAN_TILE + t * 4;

    int v0 = 0, v1 = 0, v2 = 0, v3 = 0;
    if (base + 3 < N) {
        int4 v = *(const int4*)(cnt + base);
        v0 = v.x; v1 = v.y; v2 = v.z; v3 = v.w;
    } else {
        if (base + 0 < N) v0 = cnt[base + 0];
        if (base + 1 < N) v1 = cnt[base + 1];
        if (base + 2 < N) v2 = cnt[base + 2];
        if (base + 3 < N) v3 = cnt[base + 3];
    }
    int s = v0 + v1 + v2 + v3;

    int inc = s;
#pragma unroll
    for (int off = 1; off < 64; off <<= 1) {
        int u = __shfl_up(inc, off);
        if (lane >= off) inc += u;
    }

    __shared__ int wtot[4];
    if (lane == 63) wtot[wave] = inc;
    __syncthreads();
    int woff = 0;
#pragma unroll
    for (int w = 0; w < 4; w++) woff += (w < wave) ? wtot[w] : 0;

    int excl = bsum[blockIdx.x] + woff + (inc - s);

    if (base < N) {
        int p0 = excl, p1 = p0 + v0, p2 = p1 + v1, p3 = p2 + v2;
        if (base + 3 < N) {
            *(int4*)(offs + base)   = make_int4(p0, p1, p2, p3);
            *(int4*)(cursor + base) = make_int4(p0, p1, p2, p3);
        } else {
            if (base + 0 < N) { offs[base + 0] = p0; cursor[base + 0] = p0; }
            if (base + 1 < N) { offs[base + 1] = p1; cursor[base + 1] = p1; }
            if (base + 2 < N) { offs[base + 2] = p2; cursor[base + 2] = p2; }
            if (base + 3 < N) { offs[base + 3] = p3; cursor[base + 3] = p3; }
        }
    }
    if (blockIdx.x == 0 && t == 0) offs[N] = E;
}

// ---------------------------------------------------------------------------
// Kernel 4: scatter (edge_id, src) pairs into dst-CSR order. 8B payload per
// edge (vs the old 32B records): minimal RFO/line-thrash amplification.
// ---------------------------------------------------------------------------
__global__ void scatter_es(const int* __restrict__ ei, int* __restrict__ cursor,
                           uint2* __restrict__ es, int E)
{
    int e = blockIdx.x * blockDim.x + threadIdx.x;
    if (e >= E) return;
    int s = ei[e];
    int d = ei[E + e];
    int pos = atomicAdd(&cursor[d], 1);
    es[pos] = make_uint2((unsigned)e, (unsigned)s);
}

// ---------------------------------------------------------------------------
// Kernel 5: fused layer-1 aggregation. 16 lanes per node walk the CSR
// segment (coalesced es read), gather the 128B ea row DIRECTLY (row = 2 full
// cache lines -> random but line-dense, zero waste), project e1[5]/e2
// in-loop (compute is free), gather kqv[src] (L2-hot 6.4MB table), gate,
// shfl-reduce, one h write per node. Also emits e2s[i] in CSR order
// (coalesced) for layer 2. No rec buffer, no second pass over ea.
// ---------------------------------------------------------------------------
__global__ void agg1(const uint2* __restrict__ es, const int* __restrict__ offs,
                     const float* __restrict__ ea,
                     const float* __restrict__ We1, const float* __restrict__ be1,
                     const float* __restrict__ We2, const float* __restrict__ be2,
                     const float* __restrict__ kqv, float* __restrict__ h,
                     float* __restrict__ e2s, int N)
{
    int t = threadIdx.x;
    int n = blockIdx.x * 16 + (t >> 4);
    int lane = t & 15;
    if (n >= N) return;

    int start = offs[n], end = offs[n + 1];

    const float4* drow = (const float4*)(kqv + (size_t)n * 16);
    float4 kA = drow[2];  // v3 v4 k0 k1
    float4 kB = drow[3];  // k2 k3 k4 0
    float kd0 = kA.z, kd1 = kA.w, kd2 = kB.x, kd3 = kB.y, kd4 = kB.z;

    float b10 = be1[0], b11 = be1[1], b12 = be1[2], b13 = be1[3], b14 = be1[4];
    float b20 = be2[0];

    float m0 = 0, m1 = 0, m2 = 0, m3 = 0, m4 = 0;
    for (int i = start + lane; i < end; i += 16) {
        uint2 p = es[i];
        int e = (int)p.x;
        int s = (int)p.y;

        const float4* A4 = (const float4*)(ea + (size_t)e * ED);
        // issue kqv[src] gather early
        const float4* srow = (const float4*)(kqv + (size_t)s * 16);
        float4 q0 = srow[0];  // q0 q1 q2 q3
        float4 q1 = srow[1];  // q4 v0 v1 v2
        float4 q2 = srow[2];  // v3 v4 k0 k1

        float e10 = b10, e11 = b11, e12 = b12, e13 = b13, e14 = b14, e2 = b20;
#pragma unroll
        for (int j4 = 0; j4 < 8; j4++) {
            float4 v = A4[j4];
            float av[4] = {v.x, v.y, v.z, v.w};
#pragma unroll
            for (int r = 0; r < 4; r++) {
                int j = j4 * 4 + r;
                float a = av[r];
                e10 += a * We1[j * H1 + 0];
                e11 += a * We1[j * H1 + 1];
                e12 += a * We1[j * H1 + 2];
                e13 += a * We1[j * H1 + 3];
                e14 += a * We1[j * H1 + 4];
                e2  += a * We2[j];
            }
        }

        m0 += sigf(kd0 + q0.x + 2.0f * e10) * (q1.y + e10);
        m1 += sigf(kd1 + q0.y + 2.0f * e11) * (q1.z + e11);
        m2 += sigf(kd2 + q0.z + 2.0f * e12) * (q1.w + e12);
        m3 += sigf(kd3 + q0.w + 2.0f * e13) * (q2.x + e13);
        m4 += sigf(kd4 + q1.x + 2.0f * e14) * (q2.y + e14);

        e2s[i] = e2;   // coalesced in CSR order; consumed by aggregate2
    }

#pragma unroll
    for (int off = 8; off >= 1; off >>= 1) {
        m0 += __shfl_xor(m0, off);
        m1 += __shfl_xor(m1, off);
        m2 += __shfl_xor(m2, off);
        m3 += __shfl_xor(m3, off);
        m4 += __shfl_xor(m4, off);
    }

    if (lane == 0) {
        size_t base = (size_t)n * H1;
        h[base + 0] += m0;  // h holds root term from node_proj1
        h[base + 1] += m1;
        h[base + 2] += m2;
        h[base + 3] += m3;
        h[base + 4] += m4;
    }
}

// ---------------------------------------------------------------------------
// Kernel 6: GraphNorm stats (batch_idx sorted, binary search, no atomics).
// ---------------------------------------------------------------------------
__global__ void norm_reduce(const float* __restrict__ h, const int* __restrict__ B,
                            const float* __restrict__ gw, const float* __restrict__ gb,
                            const float* __restrict__ gms,
                            float* __restrict__ scale, float* __restrict__ shift, int N)
{
    int g = blockIdx.x;

    int lo = 0, hi = N;
    while (lo < hi) { int mid = (lo + hi) >> 1; if (B[mid] < g) lo = mid + 1; else hi = mid; }
    int start = lo;
    hi = N;
    while (lo < hi) { int mid = (lo + hi) >> 1; if (B[mid] < g + 1) lo = mid + 1; else hi = mid; }
    int end = lo;

    float sum[H1] = {0, 0, 0, 0, 0};
    float sq[H1]  = {0, 0, 0, 0, 0};
    for (int i = start + threadIdx.x; i < end; i += blockDim.x) {
#pragma unroll
        for (int c = 0; c < H1; c++) {
            float v = h[(size_t)i * H1 + c];
            sum[c] += v;
            sq[c]  += v * v;
        }
    }

#pragma unroll
    for (int off = 32; off >= 1; off >>= 1) {
#pragma unroll
        for (int c = 0; c < H1; c++) {
            sum[c] += __shfl_xor(sum[c], off);
            sq[c]  += __shfl_xor(sq[c], off);
        }
    }

    __shared__ float ls[4][2 * H1];
    int wave = threadIdx.x >> 6;
    int lane = threadIdx.x & 63;
    if (lane == 0) {
#pragma unroll
        for (int c = 0; c < H1; c++) { ls[wave][c] = sum[c]; ls[wave][H1 + c] = sq[c]; }
    }
    __syncthreads();

    if (threadIdx.x == 0) {
        float cnt = fmaxf((float)(end - start), 1.0f);
#pragma unroll
        for (int c = 0; c < H1; c++) {
            float s0 = ls[0][c] + ls[1][c] + ls[2][c] + ls[3][c];
            float q0 = ls[0][H1 + c] + ls[1][H1 + c] + ls[2][H1 + c] + ls[3][H1 + c];
            float mean = s0 / cnt;
            float ms   = gms[c];
            float var  = q0 / cnt - mean * mean * ms * (2.0f - ms);
            float inv  = rsqrtf(var + 1e-5f);
            float sc   = gw[c] * inv;
            scale[g * H1 + c] = sc;
            shift[g * H1 + c] = gb[c] - sc * mean * ms;
        }
    }
}

// ---------------------------------------------------------------------------
// Kernel 7: apply norm + ReLU + layer-2 node projections.
// ---------------------------------------------------------------------------
__global__ void norm_apply_proj2(const float* __restrict__ h, const int* __restrict__ B,
                                 const float* __restrict__ scale, const float* __restrict__ shift,
                                 const float* __restrict__ Wk2, const float* __restrict__ bk2,
                                 const float* __restrict__ Wq2, const float* __restrict__ bq2,
                                 const float* __restrict__ Wv2, const float* __restrict__ bv2,
                                 const float* __restrict__ Ws2, const float* __restrict__ b2,
                                 float4* __restrict__ kqv2, float* __restrict__ root2, int N)
{
    int n = blockIdx.x * blockDim.x + threadIdx.x;
    if (n >= N) return;

    int g = B[n];
    float k2 = bk2[0], q2 = bq2[0], v2 = bv2[0], s2 = b2[0];
#pragma unroll
    for (int c = 0; c < H1; c++) {
        float hn = scale[g * H1 + c] * h[(size_t)n * H1 + c] + shift[g * H1 + c];
        hn = fmaxf(hn, 0.0f);
        k2 += hn * Wk2[c];
        q2 += hn * Wq2[c];
        v2 += hn * Wv2[c];
        s2 += hn * Ws2[c];
    }
    kqv2[n]  = make_float4(k2, q2, v2, 0.0f);
    root2[n] = s2;
}

// ---------------------------------------------------------------------------
// Kernel 8: layer-2 aggregation + final sigmoid. Coalesced es/e2s reads,
// 16B kqv2 gathers (1.6MB table, L2-hot). No atomics.
// ---------------------------------------------------------------------------
__global__ void aggregate2(const uint2* __restrict__ es, const int* __restrict__ offs,
                           const float* __restrict__ e2s,
                           const float4* __restrict__ kqv2, const float* __restrict__ root2,
                           float* __restrict__ out, int N)
{
    int t = threadIdx.x;
    int n = blockIdx.x * 16 + (t >> 4);
    int lane = t & 15;
    if (n >= N) return;

    int start = offs[n], end = offs[n + 1];
    float kd = kqv2[n].x;

    float m = 0;
    for (int i = start + lane; i < end; i += 16) {
        uint2 p = es[i];
        float e2 = e2s[i];
        float4 sv = kqv2[(int)p.y];
        m += sigf(kd + sv.y + 2.0f * e2) * (sv.z + e2);
    }

#pragma unroll
    for (int off = 8; off >= 1; off >>= 1) m += __shfl_xor(m, off);

    if (lane == 0) out[n] = sigf(root2[n] + m);
}

// ---------------------------------------------------------------------------
extern "C" void kernel_launch(void* const* d_in, const int* in_sizes, int n_in,
                              void* d_out, int out_size, void* d_ws, size_t ws_size,
                              hipStream_t stream)
{
    const float* x   = (const float*)d_in[0];
    const float* ea  = (const float*)d_in[1];
    const int*   ei  = (const int*)d_in[2];
    const int*   B   = (const int*)d_in[3];
    const float* Wk1 = (const float*)d_in[4];
    const float* bk1 = (const float*)d_in[5];
    const float* Wq1 = (const float*)d_in[6];
    const float* bq1 = (const float*)d_in[7];
    const float* Wv1 = (const float*)d_in[8];
    const float* bv1 = (const float*)d_in[9];
    const float* We1 = (const float*)d_in[10];
    const float* be1 = (const float*)d_in[11];
    const float* Ws1 = (const float*)d_in[12];
    const float* b1  = (const float*)d_in[13];
    const float* gw  = (const float*)d_in[14];
    const float* gb  = (const float*)d_in[15];
    const float* gms = (const float*)d_in[16];
    const float* Wk2 = (const float*)d_in[17];
    const float* bk2 = (const float*)d_in[18];
    const float* Wq2 = (const float*)d_in[19];
    const float* bq2 = (const float*)d_in[20];
    const float* Wv2 = (const float*)d_in[21];
    const float* bv2 = (const float*)d_in[22];
    const float* We2 = (const float*)d_in[23];
    const float* be2 = (const float*)d_in[24];
    const float* Ws2 = (const float*)d_in[25];
    const float* b2  = (const float*)d_in[26];

    const int N = in_sizes[0] / ND;   // 100000
    const int E = in_sizes[1] / ED;   // 1600000
    const int nb = (N + SCAN_TILE - 1) / SCAN_TILE;  // 98

    // Workspace layout (4B units), every segment 16B-aligned. Total ~31 MB.
    float* ws     = (float*)d_ws;
    float* kqv    = ws;                                 // N*16      (6.4 MB)
    float* h      = kqv + (size_t)N * 16;               // N*5       (2 MB)
    float* esf    = h + (size_t)N * H1;                 // E*2       (12.8 MB)
    float* e2s    = esf + (size_t)E * 2;                // E         (6.4 MB)
    int*   cnt    = (int*)(e2s + (size_t)E);            // N
    int*   offs   = cnt + N;                            // N+4 (pad)
    int*   cursor = offs + N + 4;                       // N
    int*   bsum   = cursor + N;                         // 1024
    float* scale  = (float*)(bsum + 1024);              // NG*5 = 320
    float* shift  = scale + NG * H1;                    // 320
    float* kqv2f  = shift + NG * H1;                    // N*4 (640 floats before -> 16B aligned)
    float* root2  = kqv2f + (size_t)N * 4;              // N
    float4* kqv2  = (float4*)kqv2f;
    uint2*  es    = (uint2*)esf;

    dim3 blk(256);
    dim3 gN((N + 255) / 256);
    dim3 gE((E + 255) / 256);
    dim3 gAgg((N + 15) / 16);

    hipMemsetAsync(cnt, 0, (size_t)N * sizeof(int), stream);

    hist_dst<<<gE, blk, 0, stream>>>(ei, cnt, E);
    node_proj1<<<gN, blk, 0, stream>>>(x, Wk1, bk1, Wq1, bq1, Wv1, bv1, Ws1, b1,
                                       kqv, h, N);
    scan_part<<<nb, 256, 0, stream>>>(cnt, bsum, N);
    scan_blocksums<<<1, 1024, 0, stream>>>(bsum, nb);
    scan_final<<<nb, 256, 0, stream>>>(cnt, bsum, offs, cursor, N, E);
    scatter_es<<<gE, blk, 0, stream>>>(ei, cursor, es, E);
    agg1<<<gAgg, blk, 0, stream>>>(es, offs, ea, We1, be1, We2, be2, kqv, h,
                                   e2s, N);
    norm_reduce<<<NG, blk, 0, stream>>>(h, B, gw, gb, gms, scale, shift, N);
    norm_apply_proj2<<<gN, blk, 0, stream>>>(h, B, scale, shift,
                                             Wk2, bk2, Wq2, bq2, Wv2, bv2, Ws2, b2,
                                             kqv2, root2, N);
    aggregate2<<<gAgg, blk, 0, stream>>>(es, offs, e2s, kqv2, root2,
                                         (float*)d_out, N);
}

// Round 7
// 585.974 us; speedup vs baseline: 1.5655x; 1.2649x over previous
//
#include <hip/hip_runtime.h>
#include <math.h>

#define ND 256
#define ED 32
#define H1 5
#define NG 64
#define SCAN_TILE 1024
#define CH 4096          // edges per partition block
#define BSH 9            // bucket shift: 512 nodes per bucket
#define BKT 512
#define SUBS 4           // aggregation blocks per bucket

__device__ __forceinline__ float sigf(float z) {
    return 1.0f / (1.0f + __expf(-z));
}

// ---------------------------------------------------------------------------
// Kernel 1: layer-1 node projections.
// kqv row layout (16 floats, 64B-aligned): [0..4]=q, [5..9]=v, [10..14]=k, [15]=0
// h[n][0..4] = x@Ws1 + b1  (root term; combine1 adds bucket partials later).
// ---------------------------------------------------------------------------
__global__ void node_proj1(const float* __restrict__ x,
                           const float* __restrict__ Wk, const float* __restrict__ bk,
                           const float* __restrict__ Wq, const float* __restrict__ bq,
                           const float* __restrict__ Wv, const float* __restrict__ bv,
                           const float* __restrict__ Ws, const float* __restrict__ br,
                           float* __restrict__ kqv, float* __restrict__ h, int N)
{
    int n = blockIdx.x * blockDim.x + threadIdx.x;
    if (n >= N) return;

    float acc[20];
#pragma unroll
    for (int c = 0; c < H1; c++) {
        acc[c]      = bk[c];   // k
        acc[5 + c]  = bq[c];   // q
        acc[10 + c] = bv[c];   // v
        acc[15 + c] = br[c];   // root
    }

    const float4* X4 = (const float4*)(x + (size_t)n * ND);
#pragma unroll 2
    for (int j4 = 0; j4 < ND / 4; j4++) {
        float4 xv = X4[j4];
        float xr[4] = {xv.x, xv.y, xv.z, xv.w};
#pragma unroll
        for (int r = 0; r < 4; r++) {
            int j = j4 * 4 + r;
#pragma unroll
            for (int c = 0; c < H1; c++) {
                acc[c]      += xr[r] * Wk[j * H1 + c];
                acc[5 + c]  += xr[r] * Wq[j * H1 + c];
                acc[10 + c] += xr[r] * Wv[j * H1 + c];
                acc[15 + c] += xr[r] * Ws[j * H1 + c];
            }
        }
    }

    float* row = kqv + (size_t)n * 16;
#pragma unroll
    for (int c = 0; c < H1; c++) {
        row[c]      = acc[5 + c];   // q
        row[5 + c]  = acc[10 + c];  // v
        row[10 + c] = acc[c];       // k
    }
    row[15] = 0.0f;
#pragma unroll
    for (int c = 0; c < H1; c++) h[(size_t)n * H1 + c] = acc[15 + c];
}

// ---------------------------------------------------------------------------
// Kernel 2: per-partition-block bucket histogram (bucket = dst>>9).
// gh layout: [bucket][pblock]  (nbuck * PB ints, fully written -> no memset).
// ---------------------------------------------------------------------------
__global__ void bucket_hist(const int* __restrict__ ei, int* __restrict__ gh,
                            int E, int PB, int nbuck)
{
    __shared__ int hist[256];
    int t = threadIdx.x;
    hist[t] = 0;
    __syncthreads();

    int base = blockIdx.x * CH;
#pragma unroll
    for (int k = 0; k < CH / 256; k++) {
        int i = base + k * 256 + t;
        if (i < E) atomicAdd(&hist[ei[E + i] >> BSH], 1);
    }
    __syncthreads();
    if (t < nbuck) gh[t * PB + blockIdx.x] = hist[t];
}

// ---------------------------------------------------------------------------
// Kernels 3a/3b/3c: parallel exclusive scan of gh[SN] -> gho[SN+1].
// (scan_part/scan_blocksums verbatim from the verified 654us session;
//  scan_final trimmed: no cursor output.)
// ---------------------------------------------------------------------------
__global__ void scan_part(const int* __restrict__ cnt, int* __restrict__ bsum, int N)
{
    int t = threadIdx.x;
    int base = blockIdx.x * SCAN_TILE + t * 4;
    int s = 0;
    if (base + 3 < N) {
        int4 v = *(const int4*)(cnt + base);
        s = v.x + v.y + v.z + v.w;
    } else {
        for (int i = 0; i < 4; i++) if (base + i < N) s += cnt[base + i];
    }
#pragma unroll
    for (int off = 32; off >= 1; off >>= 1) s += __shfl_xor(s, off);
    __shared__ int wsum[4];
    if ((t & 63) == 0) wsum[t >> 6] = s;
    __syncthreads();
    if (t == 0) bsum[blockIdx.x] = wsum[0] + wsum[1] + wsum[2] + wsum[3];
}

__global__ void scan_blocksums(int* __restrict__ bsum, int nb)
{
    __shared__ int a[1024], b[1024];
    int t = threadIdx.x;
    int v = (t < nb) ? bsum[t] : 0;
    a[t] = v;
    __syncthreads();
    int* in = a; int* out = b;
    for (int off = 1; off < 1024; off <<= 1) {
        out[t] = in[t] + ((t >= off) ? in[t - off] : 0);
        __syncthreads();
        int* tmp = in; in = out; out = tmp;
    }
    if (t < nb) bsum[t] = in[t] - v;  // exclusive prefix
}

__global__ void scan_final(const int* __restrict__ cnt, const int* __restrict__ bsum,
                           int* __restrict__ offs, int N, int E)
{
    int t = threadIdx.x;
    int lane = t & 63;
    int wave = t >> 6;
    int base = blockIdx.x * SCAN_TILE + t * 4;

    int v0 = 0, v1 = 0, v2 = 0, v3 = 0;
    if (base + 3 < N) {
        int4 v = *(const int4*)(cnt + base);
        v0 = v.x; v1 = v.y; v2 = v.z; v3 = v.w;
    } else {
        if (base + 0 < N) v0 = cnt[base + 0];
        if (base + 1 < N) v1 = cnt[base + 1];
        if (base + 2 < N) v2 = cnt[base + 2];
        if (base + 3 < N) v3 = cnt[base + 3];
    }
    int s = v0 + v1 + v2 + v3;

    int inc = s;
#pragma unroll
    for (int off = 1; off < 64; off <<= 1) {
        int u = __shfl_up(inc, off);
        if (lane >= off) inc += u;
    }

    __shared__ int wtot[4];
    if (lane == 63) wtot[wave] = inc;
    __syncthreads();
    int woff = 0;
#pragma unroll
    for (int w = 0; w < 4; w++) woff += (w < wave) ? wtot[w] : 0;

    int excl = bsum[blockIdx.x] + woff + (inc - s);

    if (base < N) {
        int p0 = excl, p1 = p0 + v0, p2 = p1 + v1, p3 = p2 + v2;
        if (base + 3 < N) {
            *(int4*)(offs + base) = make_int4(p0, p1, p2, p3);
        } else {
            if (base + 0 < N) offs[base + 0] = p0;
            if (base + 1 < N) offs[base + 1] = p1;
            if (base + 2 < N) offs[base + 2] = p2;
            if (base + 3 < N) offs[base + 3] = p3;
        }
    }
    if (blockIdx.x == 0 && t == 0) offs[N] = E;
}

// ---------------------------------------------------------------------------
// Kernel 4: bucket partition. Each 4096-edge block ranks its edges per
// bucket in LDS, then copies LDS->global in piecewise-consecutive runs:
// writes are coalesced bursts (~14 MB total vs 100 MB for a naive 8B
// scatter, which pays a full 64B line per write).
// bes[i] = {edge_id, src | (dst&511)<<17}, grouped by bucket.
// ---------------------------------------------------------------------------
__global__ void bucket_scatter(const int* __restrict__ ei, const int* __restrict__ gho,
                               uint2* __restrict__ bes, int E, int PB, int nbuck)
{
    __shared__ int hist[256];    // counts, then exclusive prefix
    __shared__ int pref[256];
    __shared__ int cur[256];
    __shared__ int gbase[256];
    __shared__ uint2 lrec[CH];
    __shared__ unsigned short lbuck[CH];

    int t = threadIdx.x;
    int pb = blockIdx.x;
    int base = pb * CH;
    int cnt = min(CH, E - base);

    hist[t] = 0;
    cur[t] = 0;
    gbase[t] = (t < nbuck) ? gho[t * PB + pb] : 0;
    __syncthreads();

#pragma unroll
    for (int k = 0; k < CH / 256; k++) {
        int i = base + k * 256 + t;
        if (i < E) atomicAdd(&hist[ei[E + i] >> BSH], 1);
    }
    __syncthreads();

    // exclusive prefix over 256 bucket slots (Hillis-Steele)
    int v = hist[t];
    pref[t] = v;
    __syncthreads();
    for (int off = 1; off < 256; off <<= 1) {
        int u = (t >= off) ? pref[t - off] : 0;
        __syncthreads();
        pref[t] += u;
        __syncthreads();
    }
    hist[t] = pref[t] - v;   // exclusive prefix, reuse hist
    __syncthreads();

    // place records into LDS grouped by bucket
#pragma unroll
    for (int k = 0; k < CH / 256; k++) {
        int i = base + k * 256 + t;
        if (i < E) {
            int s = ei[i];
            int d = ei[E + i];
            int b = d >> BSH;
            int r = atomicAdd(&cur[b], 1);
            int slot = hist[b] + r;
            lrec[slot]  = make_uint2((unsigned)i,
                                     (unsigned)s | ((unsigned)(d & (BKT - 1)) << 17));
            lbuck[slot] = (unsigned short)b;
        }
    }
    __syncthreads();

    // copy out: consecutive LDS slots -> consecutive global positions per run
    for (int i = t; i < cnt; i += 256) {
        int b = lbuck[i];
        bes[gbase[b] + (i - hist[b])] = lrec[i];
    }
}

// ---------------------------------------------------------------------------
// Kernel 5: layer-1 bucketed aggregation. Block j handles quarter (j&3) of
// bucket j>>2 (512 dst nodes). Reads bes coalesced, gathers the 128B ea row
// (line-dense random), projects e1[5]/e2 in-loop, reads k[dst] from a 10KB
// LDS preload, gathers q/v of src from the LLC-hot kqv table, gates, and
// accumulates into a 10KB LDS accumulator via ds_add_f32 (no global
// atomics). Emits e2b bucket-ordered (coalesced) for layer 2, and its
// 512x5 partial to hpart[j].
// ---------------------------------------------------------------------------
__global__ void agg1_bucket(const uint2* __restrict__ bes, const int* __restrict__ gho,
                            const float* __restrict__ ea,
                            const float* __restrict__ We1, const float* __restrict__ be1,
                            const float* __restrict__ We2, const float* __restrict__ be2,
                            const float* __restrict__ kqv,
                            float* __restrict__ hpart, float* __restrict__ e2b,
                            int N, int PB)
{
    __shared__ float lacc[BKT * H1];   // 10 KB accumulator
    __shared__ float lkd[BKT * H1];    // 10 KB k[dst] cache

    int t = threadIdx.x;
    int j = blockIdx.x;
    int g = j >> 2;
    int sub = j & 3;

    int start = gho[g * PB];
    int end   = gho[(g + 1) * PB];

    for (int i = t; i < BKT * H1; i += 256) lacc[i] = 0.0f;
    int nodebase = g << BSH;
    for (int nn = t; nn < BKT; nn += 256) {
        int node = nodebase + nn;
        if (node < N) {
            const float* kr = kqv + (size_t)node * 16 + 10;
#pragma unroll
            for (int c = 0; c < H1; c++) lkd[nn * H1 + c] = kr[c];
        } else {
#pragma unroll
            for (int c = 0; c < H1; c++) lkd[nn * H1 + c] = 0.0f;
        }
    }
    __syncthreads();

    int len = end - start;
    int quarter = (len + 3) >> 2;
    int r0 = start + sub * quarter;
    int r1 = min(r0 + quarter, end);

    float b10 = be1[0], b11 = be1[1], b12 = be1[2], b13 = be1[3], b14 = be1[4];
    float b20 = be2[0];

    for (int i = r0 + t; i < r1; i += 256) {
        uint2 p = bes[i];
        int e  = (int)p.x;
        int s  = (int)(p.y & 0x1FFFFu);
        int dl = (int)(p.y >> 17);

        const float4* A4 = (const float4*)(ea + (size_t)e * ED);
        const float4* srow = (const float4*)(kqv + (size_t)s * 16);
        float4 q0 = srow[0];  // q0 q1 q2 q3
        float4 q1 = srow[1];  // q4 v0 v1 v2
        float4 q2 = srow[2];  // v3 v4 k0 k1

        float e10 = b10, e11 = b11, e12 = b12, e13 = b13, e14 = b14, e2 = b20;
#pragma unroll
        for (int j4 = 0; j4 < 8; j4++) {
            float4 av = A4[j4];
            float ar[4] = {av.x, av.y, av.z, av.w};
#pragma unroll
            for (int r = 0; r < 4; r++) {
                int jj = j4 * 4 + r;
                float a = ar[r];
                e10 += a * We1[jj * H1 + 0];
                e11 += a * We1[jj * H1 + 1];
                e12 += a * We1[jj * H1 + 2];
                e13 += a * We1[jj * H1 + 3];
                e14 += a * We1[jj * H1 + 4];
                e2  += a * We2[jj];
            }
        }

        const float* kd = &lkd[dl * H1];
        float m0 = sigf(kd[0] + q0.x + 2.0f * e10) * (q1.y + e10);
        float m1 = sigf(kd[1] + q0.y + 2.0f * e11) * (q1.z + e11);
        float m2 = sigf(kd[2] + q0.z + 2.0f * e12) * (q1.w + e12);
        float m3 = sigf(kd[3] + q0.w + 2.0f * e13) * (q2.x + e13);
        float m4 = sigf(kd[4] + q1.x + 2.0f * e14) * (q2.y + e14);

        float* acc = &lacc[dl * H1];
        atomicAdd(acc + 0, m0);
        atomicAdd(acc + 1, m1);
        atomicAdd(acc + 2, m2);
        atomicAdd(acc + 3, m3);
        atomicAdd(acc + 4, m4);

        e2b[i] = e2;   // bucket-ordered, coalesced
    }
    __syncthreads();

    float* hp = hpart + (size_t)j * (BKT * H1);
    for (int i = t; i < BKT * H1; i += 256) hp[i] = lacc[i];
}

// ---------------------------------------------------------------------------
// Kernel 6: combine bucket partials into h (h holds the root term).
// ---------------------------------------------------------------------------
__global__ void combine1(float* __restrict__ h, const float* __restrict__ hpart, int N)
{
    int n = blockIdx.x * blockDim.x + threadIdx.x;
    if (n >= N) return;
    int g = n >> BSH, dl = n & (BKT - 1);
    size_t pb = (size_t)(g * SUBS) * (BKT * H1) + dl * H1;
#pragma unroll
    for (int c = 0; c < H1; c++) {
        h[(size_t)n * H1 + c] += hpart[pb + c]
                               + hpart[pb + (BKT * H1) + c]
                               + hpart[pb + 2 * (BKT * H1) + c]
                               + hpart[pb + 3 * (BKT * H1) + c];
    }
}

// ---------------------------------------------------------------------------
// Kernel 7: GraphNorm stats (batch_idx sorted, binary search, no atomics).
// ---------------------------------------------------------------------------
__global__ void norm_reduce(const float* __restrict__ h, const int* __restrict__ B,
                            const float* __restrict__ gw, const float* __restrict__ gb,
                            const float* __restrict__ gms,
                            float* __restrict__ scale, float* __restrict__ shift, int N)
{
    int g = blockIdx.x;

    int lo = 0, hi = N;
    while (lo < hi) { int mid = (lo + hi) >> 1; if (B[mid] < g) lo = mid + 1; else hi = mid; }
    int start = lo;
    hi = N;
    while (lo < hi) { int mid = (lo + hi) >> 1; if (B[mid] < g + 1) lo = mid + 1; else hi = mid; }
    int end = lo;

    float sum[H1] = {0, 0, 0, 0, 0};
    float sq[H1]  = {0, 0, 0, 0, 0};
    for (int i = start + threadIdx.x; i < end; i += blockDim.x) {
#pragma unroll
        for (int c = 0; c < H1; c++) {
            float v = h[(size_t)i * H1 + c];
            sum[c] += v;
            sq[c]  += v * v;
        }
    }

#pragma unroll
    for (int off = 32; off >= 1; off >>= 1) {
#pragma unroll
        for (int c = 0; c < H1; c++) {
            sum[c] += __shfl_xor(sum[c], off);
            sq[c]  += __shfl_xor(sq[c], off);
        }
    }

    __shared__ float ls[4][2 * H1];
    int wave = threadIdx.x >> 6;
    int lane = threadIdx.x & 63;
    if (lane == 0) {
#pragma unroll
        for (int c = 0; c < H1; c++) { ls[wave][c] = sum[c]; ls[wave][H1 + c] = sq[c]; }
    }
    __syncthreads();

    if (threadIdx.x == 0) {
        float cnt = fmaxf((float)(end - start), 1.0f);
#pragma unroll
        for (int c = 0; c < H1; c++) {
            float s0 = ls[0][c] + ls[1][c] + ls[2][c] + ls[3][c];
            float q0 = ls[0][H1 + c] + ls[1][H1 + c] + ls[2][H1 + c] + ls[3][H1 + c];
            float mean = s0 / cnt;
            float ms   = gms[c];
            float var  = q0 / cnt - mean * mean * ms * (2.0f - ms);
            float inv  = rsqrtf(var + 1e-5f);
            float sc   = gw[c] * inv;
            scale[g * H1 + c] = sc;
            shift[g * H1 + c] = gb[c] - sc * mean * ms;
        }
    }
}

// ---------------------------------------------------------------------------
// Kernel 8: apply norm + ReLU + layer-2 node projections.
// ---------------------------------------------------------------------------
__global__ void norm_apply_proj2(const float* __restrict__ h, const int* __restrict__ B,
                                 const float* __restrict__ scale, const float* __restrict__ shift,
                                 const float* __restrict__ Wk2, const float* __restrict__ bk2,
                                 const float* __restrict__ Wq2, const float* __restrict__ bq2,
                                 const float* __restrict__ Wv2, const float* __restrict__ bv2,
                                 const float* __restrict__ Ws2, const float* __restrict__ b2,
                                 float4* __restrict__ kqv2, float* __restrict__ root2, int N)
{
    int n = blockIdx.x * blockDim.x + threadIdx.x;
    if (n >= N) return;

    int g = B[n];
    float k2 = bk2[0], q2 = bq2[0], v2 = bv2[0], s2 = b2[0];
#pragma unroll
    for (int c = 0; c < H1; c++) {
        float hn = scale[g * H1 + c] * h[(size_t)n * H1 + c] + shift[g * H1 + c];
        hn = fmaxf(hn, 0.0f);
        k2 += hn * Wk2[c];
        q2 += hn * Wq2[c];
        v2 += hn * Wv2[c];
        s2 += hn * Ws2[c];
    }
    kqv2[n]  = make_float4(k2, q2, v2, 0.0f);
    root2[n] = s2;
}

// ---------------------------------------------------------------------------
// Kernel 9: layer-2 bucketed aggregation. Coalesced bes/e2b reads, 16B
// kqv2[src] gathers (1.6MB table, cache-hot), LDS accumulation.
// ---------------------------------------------------------------------------
__global__ void agg2_bucket(const uint2* __restrict__ bes, const int* __restrict__ gho,
                            const float* __restrict__ e2b,
                            const float4* __restrict__ kqv2,
                            float* __restrict__ mpart, int N, int PB)
{
    __shared__ float lm[BKT];
    __shared__ float lkd2[BKT];

    int t = threadIdx.x;
    int j = blockIdx.x;
    int g = j >> 2;
    int sub = j & 3;

    int start = gho[g * PB];
    int end   = gho[(g + 1) * PB];

    int nodebase = g << BSH;
    for (int nn = t; nn < BKT; nn += 256) {
        lm[nn] = 0.0f;
        int node = nodebase + nn;
        lkd2[nn] = (node < N) ? kqv2[node].x : 0.0f;
    }
    __syncthreads();

    int len = end - start;
    int quarter = (len + 3) >> 2;
    int r0 = start + sub * quarter;
    int r1 = min(r0 + quarter, end);

    for (int i = r0 + t; i < r1; i += 256) {
        uint2 p = bes[i];
        int s  = (int)(p.y & 0x1FFFFu);
        int dl = (int)(p.y >> 17);
        float e2 = e2b[i];
        float4 sv = kqv2[s];
        float m = sigf(lkd2[dl] + sv.y + 2.0f * e2) * (sv.z + e2);
        atomicAdd(&lm[dl], m);
    }
    __syncthreads();

    float* mp = mpart + (size_t)j * BKT;
    for (int i = t; i < BKT; i += 256) mp[i] = lm[i];
}

// ---------------------------------------------------------------------------
// Kernel 10: final combine + sigmoid.
// ---------------------------------------------------------------------------
__global__ void finalize2(const float* __restrict__ root2, const float* __restrict__ mpart,
                          float* __restrict__ out, int N)
{
    int n = blockIdx.x * blockDim.x + threadIdx.x;
    if (n >= N) return;
    int g = n >> BSH, dl = n & (BKT - 1);
    size_t pb = (size_t)(g * SUBS) * BKT + dl;
    out[n] = sigf(root2[n] + mpart[pb] + mpart[pb + BKT]
                           + mpart[pb + 2 * BKT] + mpart[pb + 3 * BKT]);
}

// ---------------------------------------------------------------------------
extern "C" void kernel_launch(void* const* d_in, const int* in_sizes, int n_in,
                              void* d_out, int out_size, void* d_ws, size_t ws_size,
                              hipStream_t stream)
{
    const float* x   = (const float*)d_in[0];
    const float* ea  = (const float*)d_in[1];
    const int*   ei  = (const int*)d_in[2];
    const int*   B   = (const int*)d_in[3];
    const float* Wk1 = (const float*)d_in[4];
    const float* bk1 = (const float*)d_in[5];
    const float* Wq1 = (const float*)d_in[6];
    const float* bq1 = (const float*)d_in[7];
    const float* Wv1 = (const float*)d_in[8];
    const float* bv1 = (const float*)d_in[9];
    const float* We1 = (const float*)d_in[10];
    const float* be1 = (const float*)d_in[11];
    const float* Ws1 = (const float*)d_in[12];
    const float* b1  = (const float*)d_in[13];
    const float* gw  = (const float*)d_in[14];
    const float* gb  = (const float*)d_in[15];
    const float* gms = (const float*)d_in[16];
    const float* Wk2 = (const float*)d_in[17];
    const float* bk2 = (const float*)d_in[18];
    const float* Wq2 = (const float*)d_in[19];
    const float* bq2 = (const float*)d_in[20];
    const float* Wv2 = (const float*)d_in[21];
    const float* bv2 = (const float*)d_in[22];
    const float* We2 = (const float*)d_in[23];
    const float* be2 = (const float*)d_in[24];
    const float* Ws2 = (const float*)d_in[25];
    const float* b2  = (const float*)d_in[26];

    const int N  = in_sizes[0] / ND;              // 100000
    const int E  = in_sizes[1] / ED;              // 1600000
    const int PB = (E + CH - 1) / CH;             // 391 partition blocks
    const int nbuck = (N + BKT - 1) / BKT;        // 196 buckets
    const int SN = nbuck * PB;                    // 76636 scan elements
    const int nbs = (SN + SCAN_TILE - 1) / SCAN_TILE;  // 75 (<=1024)
    const int NBLK = nbuck * SUBS;                // 784 aggregation blocks

    // Workspace layout (4B units), every segment 16B-aligned. Total ~40 MB.
    float* ws    = (float*)d_ws;
    float* kqv   = ws;                                  // N*16   (6.4 MB)
    float* h     = kqv + (size_t)N * 16;                // N*5    (2 MB)
    float* besf  = h + (size_t)N * H1;                  // E*2    (12.8 MB)
    float* e2b   = besf + (size_t)E * 2;                // E      (6.4 MB)
    int*   gh    = (int*)(e2b + (size_t)E);             // SN     (0.3 MB)
    int*   gho   = gh + SN;                             // SN+4   (0.3 MB)
    int*   bsum  = gho + SN + 4;                        // 1024
    float* hpart = (float*)(bsum + 1024);               // NBLK*2560 (8 MB)
    float* mpart = hpart + (size_t)NBLK * (BKT * H1);   // NBLK*512  (1.6 MB)
    float* scale = mpart + (size_t)NBLK * BKT;          // NG*5
    float* shift = scale + NG * H1;                     // NG*5
    float* kqv2f = shift + NG * H1;                     // N*4   (640 before -> aligned)
    float* root2 = kqv2f + (size_t)N * 4;               // N
    float4* kqv2 = (float4*)kqv2f;
    uint2*  bes  = (uint2*)besf;

    dim3 blk(256);
    dim3 gN((N + 255) / 256);

    node_proj1<<<gN, blk, 0, stream>>>(x, Wk1, bk1, Wq1, bq1, Wv1, bv1, Ws1, b1,
                                       kqv, h, N);
    bucket_hist<<<PB, blk, 0, stream>>>(ei, gh, E, PB, nbuck);
    scan_part<<<nbs, 256, 0, stream>>>(gh, bsum, SN);
    scan_blocksums<<<1, 1024, 0, stream>>>(bsum, nbs);
    scan_final<<<nbs, 256, 0, stream>>>(gh, bsum, gho, SN, E);
    bucket_scatter<<<PB, blk, 0, stream>>>(ei, gho, bes, E, PB, nbuck);
    agg1_bucket<<<NBLK, blk, 0, stream>>>(bes, gho, ea, We1, be1, We2, be2, kqv,
                                          hpart, e2b, N, PB);
    combine1<<<gN, blk, 0, stream>>>(h, hpart, N);
    norm_reduce<<<NG, blk, 0, stream>>>(h, B, gw, gb, gms, scale, shift, N);
    norm_apply_proj2<<<gN, blk, 0, stream>>>(h, B, scale, shift,
                                             Wk2, bk2, Wq2, bq2, Wv2, bv2, Ws2, b2,
                                             kqv2, root2, N);
    agg2_bucket<<<NBLK, blk, 0, stream>>>(bes, gho, e2b, kqv2, mpart, N, PB);
    finalize2<<<gN, blk, 0, stream>>>(root2, mpart, (float*)d_out, N);
}